// Round 1
// baseline (380.826 us; speedup 1.0000x reference)
//
#include <hip/hip_runtime.h>

#define N_ROWS 8192
#define N_COLS 10000
#define SCALE  64.0f
#define BLOCK  256

// Single-block gather + reduce. Only ~0.55 MB of real traffic; launch-latency
// bound, so one kernel / one block / no atomics is the right shape.
__global__ __launch_bounds__(BLOCK) void Center_11184094839250_kernel(
    const float* __restrict__ feature,
    const int*   __restrict__ label,
    float*       __restrict__ out) {
    const int tid = threadIdx.x;

    float sum = 0.0f;
    // 32 independent gathered loads per thread; unrolled so they all go
    // in flight together (latency hiding via ILP, not occupancy).
    #pragma unroll
    for (int i = tid; i < N_ROWS; i += BLOCK) {
        const int l = label[i];
        sum += feature[(size_t)i * N_COLS + (size_t)l];
    }

    // Wave-64 shuffle reduction.
    #pragma unroll
    for (int off = 32; off > 0; off >>= 1)
        sum += __shfl_down(sum, off, 64);

    __shared__ float wave_sums[BLOCK / 64];
    const int wave = tid >> 6;
    const int lane = tid & 63;
    if (lane == 0) wave_sums[wave] = sum;
    __syncthreads();

    if (tid == 0) {
        float total = 0.0f;
        #pragma unroll
        for (int w = 0; w < BLOCK / 64; ++w) total += wave_sums[w];
        out[0] = 2.0f - 2.0f * (total / SCALE) / (float)N_ROWS;
    }
}

extern "C" void kernel_launch(void* const* d_in, const int* in_sizes, int n_in,
                              void* d_out, int out_size, void* d_ws, size_t ws_size,
                              hipStream_t stream) {
    const float* feature = (const float*)d_in[0];
    const int*   label   = (const int*)d_in[1];
    float*       out     = (float*)d_out;
    Center_11184094839250_kernel<<<1, BLOCK, 0, stream>>>(feature, label, out);
}

// Round 2
// 350.993 us; speedup vs baseline: 1.0850x; 1.0850x over previous
//
#include <hip/hip_runtime.h>

#define N_ROWS 8192
#define N_COLS 10000
#define SCALE  64.0f
#define NBLK   128   // 128 blocks x 64 threads = one row per thread

// Kernel 1: one wave per block, one gathered row element per thread.
// 128 blocks spread across 128 CUs -> each CU has only 64 outstanding
// HBM misses, all issued back-to-back -> ~one memory round-trip total.
__global__ __launch_bounds__(64) void center_partial(
    const float* __restrict__ feature,
    const int*   __restrict__ label,
    float*       __restrict__ partial) {
    const int i = blockIdx.x * 64 + threadIdx.x;   // 0..8191, always in range
    const int l = label[i];                        // coalesced 256B/wave
    float v = feature[(size_t)i * N_COLS + (size_t)l];  // 1 cacheline/lane

    #pragma unroll
    for (int off = 32; off > 0; off >>= 1)
        v += __shfl_down(v, off, 64);

    if (threadIdx.x == 0) partial[blockIdx.x] = v;
}

// Kernel 2: reduce the 128 partials, apply the loss formula.
__global__ __launch_bounds__(128) void center_final(
    const float* __restrict__ partial,
    float*       __restrict__ out) {
    const int tid = threadIdx.x;
    float v = partial[tid];

    #pragma unroll
    for (int off = 32; off > 0; off >>= 1)
        v += __shfl_down(v, off, 64);

    __shared__ float wsum[2];
    if ((tid & 63) == 0) wsum[tid >> 6] = v;
    __syncthreads();

    if (tid == 0) {
        const float total = wsum[0] + wsum[1];
        out[0] = 2.0f - 2.0f * (total / SCALE) / (float)N_ROWS;
    }
}

extern "C" void kernel_launch(void* const* d_in, const int* in_sizes, int n_in,
                              void* d_out, int out_size, void* d_ws, size_t ws_size,
                              hipStream_t stream) {
    const float* feature = (const float*)d_in[0];
    const int*   label   = (const int*)d_in[1];
    float*       out     = (float*)d_out;
    float*       partial = (float*)d_ws;   // 128 floats, fully overwritten

    center_partial<<<NBLK, 64, 0, stream>>>(feature, label, partial);
    center_final<<<1, NBLK, 0, stream>>>(partial, out);
}

// Round 3
// 349.167 us; speedup vs baseline: 1.0907x; 1.0052x over previous
//
#include <hip/hip_runtime.h>

#define N_ROWS 8192
#define N_COLS 10000
#define SCALE  64.0f
#define NBLK   128   // 128 blocks x 64 threads = one row per thread

// Kernel 1: one wave per block, one gathered row element per thread.
// 128 blocks spread across CUs -> 64 outstanding HBM misses per CU, all
// issued together -> ~one memory round-trip total (label load -> gather).
__global__ __launch_bounds__(64) void center_partial(
    const float* __restrict__ feature,
    const int*   __restrict__ label,
    float*       __restrict__ partial) {
    const int i = blockIdx.x * 64 + threadIdx.x;   // 0..8191, always in range
    const int l = label[i];                        // coalesced 256B/wave
    float v = feature[(size_t)i * N_COLS + (size_t)l];  // 1 cacheline/lane

    #pragma unroll
    for (int off = 32; off > 0; off >>= 1)
        v += __shfl_down(v, off, 64);

    if (threadIdx.x == 0) partial[blockIdx.x] = v;
}

// Kernel 2: single wave, 2 partials/lane, shuffle-reduce, write the loss.
// No LDS, no __syncthreads -- minimum possible epilogue.
__global__ __launch_bounds__(64) void center_final(
    const float* __restrict__ partial,
    float*       __restrict__ out) {
    const int tid = threadIdx.x;
    float v = partial[tid] + partial[tid + 64];

    #pragma unroll
    for (int off = 32; off > 0; off >>= 1)
        v += __shfl_down(v, off, 64);

    if (tid == 0)
        out[0] = 2.0f - 2.0f * (v / SCALE) / (float)N_ROWS;
}

extern "C" void kernel_launch(void* const* d_in, const int* in_sizes, int n_in,
                              void* d_out, int out_size, void* d_ws, size_t ws_size,
                              hipStream_t stream) {
    const float* feature = (const float*)d_in[0];
    const int*   label   = (const int*)d_in[1];
    float*       out     = (float*)d_out;
    float*       partial = (float*)d_ws;   // 128 floats, fully overwritten

    center_partial<<<NBLK, 64, 0, stream>>>(feature, label, partial);
    center_final<<<1, 64, 0, stream>>>(partial, out);
}